// Round 9
// baseline (237.559 us; speedup 1.0000x reference)
//
#include <hip/hip_runtime.h>

typedef unsigned short u16;
typedef unsigned int u32;
typedef float f32x4 __attribute__((ext_vector_type(4)));
typedef __bf16 bf16x8 __attribute__((ext_vector_type(8)));
typedef unsigned short u16x8 __attribute__((ext_vector_type(8)));
typedef unsigned short u16x4 __attribute__((ext_vector_type(4)));
typedef unsigned int u32x4 __attribute__((ext_vector_type(4)));

// hardware RNE f32->bf16 (R6-proven)
__device__ inline u16 f2bf(float f) {
    return __builtin_bit_cast(u16, (__bf16)f);
}

// async global->LDS DMA, 16B/lane; LDS dst is wave-uniform base + lane*16.
__device__ inline void gll16(const u16* g, u16* l) {
    u16* gnc = const_cast<u16*>(g);
    __builtin_amdgcn_global_load_lds((__attribute__((address_space(1))) u32*)gnc,
                                     (__attribute__((address_space(3))) u32*)l,
                                     16, 0, 0);
}

#define MFMA(a, b, c) __builtin_amdgcn_mfma_f32_16x16x32_bf16((a), (b), (c), 0, 0, 0)

// Fixed-shift softmax (R5-R8 proven): p = exp2(q'.k - C_SHIFT),
// q' = q * 0.125*log2(e).  Shift-invariant => exact.
#define C_SHIFT 17.3123405f
#define Q_SCALE 0.1803368801f   // 0.125 * log2(e)

// ---------------------------------------------------------------------------
// Kernel 0: one-shot fp32->bf16 conversion of X, w_qkv, w_out. (R7-proven)
// ---------------------------------------------------------------------------
__global__ __launch_bounds__(256)
void cvt_kernel(const float* __restrict__ X, const float* __restrict__ Wq,
                const float* __restrict__ Wo, u16* __restrict__ Xb,
                u16* __restrict__ Wqb, u16* __restrict__ Wob)
{
    int i = blockIdx.x * 256 + threadIdx.x;      // vec4 index
    const float* src; u16* dst; int off;
    if (i < 1572864)       { src = X;  dst = Xb;  off = i; }
    else if (i < 1683456)  { src = Wq; dst = Wqb; off = i - 1572864; }
    else                   { src = Wo; dst = Wob; off = i - 1683456; }
    f32x4 v = *(const f32x4*)&src[off * 4];
    u16x4 p;
    for (int k = 0; k < 4; ++k) p[k] = f2bf(v[k]);
    *(u16x4*)&dst[off * 4] = p;
}

// ---------------------------------------------------------------------------
// Kernel 1: QKV projection, 128x128 tile.  R17: LDS-FREE direct-load GEMM.
// K=384 is 12 k-steps; X (12.6MB bf16) is L3-resident, W (0.88MB) L2-resident
// -- staging through LDS was pure overhead (guide: don't stage what L2-fits;
// both GEMMs showed all-pipes-idle stall signatures from the short barrier-
// serialized staging loop).  Fragments load straight from global: addr =
// row(l15)*768B + quad*16B -> quads 0..3 of one l15 = one 64B line; 1KB per
// instruction, perfectly coalesced.  No barriers anywhere; compiler pipelines
// loads freely.  Same flattened k-order as R16 -> bit-identical output.
// Swapped MFMA operands + vectorized epilogue kept verbatim from R16.
// ---------------------------------------------------------------------------
__global__ __launch_bounds__(256)
void qkv_kernel(const u16* __restrict__ Xb, const u16* __restrict__ Wqb,
                const float* __restrict__ B, u16* __restrict__ Qo,
                u16* __restrict__ Ko, u16* __restrict__ VTo)
{
    const int tid = threadIdx.x;
    const int m0 = blockIdx.x * 128;
    const int n0 = blockIdx.y * 128;              // 9 tiles over 1152
    const int wv = tid >> 6, lane = tid & 63;
    const int l15 = lane & 15, quad = lane >> 4;
    const int mw = (wv & 1) * 64, nw = (wv >> 1) * 64;

    const u16* xb = &Xb[(m0 + mw + l15) * 384 + quad * 8];
    const u16* wb = &Wqb[(n0 + nw + l15) * 384 + quad * 8];

    f32x4 acc[4][4] = {};                         // [mi][nj]; D[n-dim][m-dim]
#pragma unroll
    for (int ks = 0; ks < 12; ++ks) {             // k-steps of 32
        const int ko = ks * 32;
        bf16x8 a[4], bf[4];
#pragma unroll
        for (int mi = 0; mi < 4; ++mi)
            a[mi] = *(const bf16x8*)(xb + mi * 16 * 384 + ko);
#pragma unroll
        for (int nj = 0; nj < 4; ++nj)
            bf[nj] = *(const bf16x8*)(wb + nj * 16 * 384 + ko);
#pragma unroll
        for (int mi = 0; mi < 4; ++mi)
#pragma unroll
            for (int nj = 0; nj < 4; ++nj)
                acc[mi][nj] = MFMA(bf[nj], a[mi], acc[mi][nj]);  // SWAPPED
    }
    // epilogue (R16-proven): D[col = n0+nw+nj*16+quad*4+r][row gm = ...+l15]
#pragma unroll
    for (int nj = 0; nj < 4; ++nj) {
        const int colb = n0 + nw + nj * 16 + quad * 4;   // + r, r=0..3
        const int t = colb / 384;                 // uniform per (block,wv,nj)
        const int hd = (colb % 384) / 64;         // head, uniform (16-block)
        const int dh0 = colb & 63;                // per-quad, +r consecutive
        const f32x4 bv = *(const f32x4*)&B[colb]; // aligned: colb % 4 == 0
#pragma unroll
        for (int mi = 0; mi < 4; ++mi) {
            const int gm = m0 + mw + mi * 16 + l15;
            const int bb = gm >> 11, n = gm & 2047;
            const int bh = bb * 6 + hd;
            if (t == 0) {
                u16x4 p;
#pragma unroll
                for (int r = 0; r < 4; ++r)
                    p[r] = f2bf((acc[mi][nj][r] + bv[r]) * Q_SCALE);
                *(u16x4*)&Qo[(bh * 2048 + n) * 64 + dh0] = p;
            } else if (t == 1) {
                u16x4 p;
#pragma unroll
                for (int r = 0; r < 4; ++r)
                    p[r] = f2bf(acc[mi][nj][r] + bv[r]);
                *(u16x4*)&Ko[(bh * 2048 + n) * 64 + dh0] = p;
            } else {
                // sigma permutation of n within each 32-key half (R14):
                // key kk = c*16+q4*4+rr -> pos q4*8+c*4+rr
                const int nn = (n & ~31) | (((n >> 2) & 3) << 3)
                             | (((n >> 4) & 1) << 2) | (n & 3);
#pragma unroll
                for (int r = 0; r < 4; ++r)
                    VTo[(bh * 64 + dh0 + r) * 2048 + nn] =
                        f2bf(acc[mi][nj][r] + bv[r]);
            }
        }
    }
}

// ---------------------------------------------------------------------------
// Kernel 2: flash attention.  R14 (FROZEN control at ~76us, bank conflicts
// == 0).  In-register P via key-permuted VT (sigma) and pi-ordered PV
// operands; key-split waves; single-barrier dbuf gll16 staging.
// ---------------------------------------------------------------------------
__global__ __launch_bounds__(512)
void attn_kernel(const u16* __restrict__ Q, const u16* __restrict__ K,
                 const u16* __restrict__ VT, u16* __restrict__ O)
{
    __shared__ __align__(128) u16 Ks[2][64][64];
    __shared__ __align__(128) u16 VTs[2][64][64];
    __shared__ __align__(16) float lbuf[128];

    const int tid = threadIdx.x;
    // XCD swizzle: lin = by*16+bx; xcd = lin%8 gets contiguous lin2 chunk.
    const int lin = blockIdx.y * 16 + blockIdx.x;
    const int lin2 = (lin & 7) * 96 + (lin >> 3);
    const int bh = lin2 >> 4;
    const int q0 = (lin2 & 15) * 128;
    const int wv = tid >> 6, lane = tid & 63;
    const int l15 = lane & 15, quad = lane >> 4;
    const int qsub = wv & 3, kh = wv >> 2;

    // Q fragments for this wave's 32 q-rows (B-operand: n=l15, k=quad*8+j)
    bf16x8 qf[2][2];
#pragma unroll
    for (int qb = 0; qb < 2; ++qb) {
        const u16* qptr = &Q[(bh * 2048 + q0 + qsub * 32 + qb * 16 + l15) * 64 + quad * 8];
        qf[qb][0] = *(const bf16x8*)qptr;
        qf[qb][1] = *(const bf16x8*)(qptr + 32);
    }

    // gll staging: wave wv covers rows wv*8 .. wv*8+7 (1KB) of each buffer.
    const int lr = lane >> 3;
    const int gsrc = (lane & 7) ^ lr;
    const u16* ksrc = &K[(bh * 2048 + wv * 8 + lr) * 64 + gsrc * 8];   // +4096/tile
    const u16* vsrc = &VT[(bh * 64 + wv * 8 + lr) * 2048 + gsrc * 8];  // +64/tile
    const int swz = (quad ^ (l15 & 7)) * 8;                  // read-side swizzle

    const f32x4 cinit = {-C_SHIFT, -C_SHIFT, -C_SHIFT, -C_SHIFT};
    float l_part[2] = {};
    f32x4 acc[2][4] = {};                     // [qb][ct=dh-block], key-half partial

    // prologue: stage tile 0 into buffer 0
    gll16(ksrc, &Ks[0][wv * 8][0]);
    gll16(vsrc, &VTs[0][wv * 8][0]);

    for (int j = 0; j < 32; ++j) {
        const int cur = j & 1;
        __syncthreads();
        if (j < 31) {
            gll16(ksrc + (j + 1) * 4096, &Ks[cur ^ 1][wv * 8][0]);
            gll16(vsrc + (j + 1) * 64, &VTs[cur ^ 1][wv * 8][0]);
        }

        // S^T over this wave's key-half: key = kh*32 + c*16 + quad*4 + r,
        // q = l15.  exp2 results packed straight into PV A-frag u32s.
        u32 w[2][2][2];                       // [qb][c][h]: keys (.. +2h, +2h+1)
#pragma unroll
        for (int c = 0; c < 2; ++c) {
            const u16* krow = &Ks[cur][kh * 32 + c * 16 + l15][0];
            bf16x8 a0 = *(const bf16x8*)(krow + swz);
            bf16x8 a1 = *(const bf16x8*)(krow + (swz ^ 32));
#pragma unroll
            for (int qb = 0; qb < 2; ++qb) {
                f32x4 s = MFMA(a0, qf[qb][0], cinit);
                s = MFMA(a1, qf[qb][1], s);
                float p0 = __builtin_amdgcn_exp2f(s[0]);
                float p1 = __builtin_amdgcn_exp2f(s[1]);
                float p2 = __builtin_amdgcn_exp2f(s[2]);
                float p3 = __builtin_amdgcn_exp2f(s[3]);
                l_part[qb] += p0;             // same add order as R12 (exact)
                l_part[qb] += p1;
                l_part[qb] += p2;
                l_part[qb] += p3;
                w[qb][c][0] = (u32)f2bf(p0) | ((u32)f2bf(p1) << 16);
                w[qb][c][1] = (u32)f2bf(p2) | ((u32)f2bf(p3) << 16);
            }
        }

        // PV A-frags: pure register renaming under pi (no shuffles, no LDS).
        bf16x8 pf[2];
#pragma unroll
        for (int qb = 0; qb < 2; ++qb) {
            u32x4 t = {w[qb][0][0], w[qb][0][1], w[qb][1][0], w[qb][1][1]};
            pf[qb] = __builtin_bit_cast(bf16x8, t);
        }

        // PV: B-frag = sigma-permuted VT under the same pi -> single
        // proven-swizzled b128 per dh-block, reused over 2 q-blocks.
#pragma unroll
        for (int ct = 0; ct < 4; ++ct) {
            bf16x8 bv = *(const bf16x8*)(&VTs[cur][ct * 16 + l15][0] + (swz ^ (kh << 5)));
#pragma unroll
            for (int qb = 0; qb < 2; ++qb)
                acc[qb][ct] = MFMA(pf[qb], bv, acc[qb][ct]);
        }
    }

    // ---- epilogue: cross-wave (key-half) reduction, then normalize+store.
    float lh[2];
#pragma unroll
    for (int qb = 0; qb < 2; ++qb) {
        float t = l_part[qb];
        t += __shfl_xor(t, 16);
        t += __shfl_xor(t, 32);
        lh[qb] = t;
    }
    __syncthreads();      // all waves done with Ks/VTs tile data
    if (kh == 1) {
        float* sb = (qsub < 2) ? (float*)&Ks[qsub][0][0] : (float*)&VTs[qsub - 2][0][0];
#pragma unroll
        for (int qb = 0; qb < 2; ++qb)
#pragma unroll
            for (int ct = 0; ct < 4; ++ct)
                *(f32x4*)&sb[((qb * 4 + ct) * 64 + lane) * 4] = acc[qb][ct];
        if (quad == 0) {
            lbuf[qsub * 32 + l15] = lh[0];
            lbuf[qsub * 32 + 16 + l15] = lh[1];
        }
    }
    __syncthreads();
    if (kh == 0) {
        float* sb = (qsub < 2) ? (float*)&Ks[qsub][0][0] : (float*)&VTs[qsub - 2][0][0];
#pragma unroll
        for (int qb = 0; qb < 2; ++qb)
#pragma unroll
            for (int ct = 0; ct < 4; ++ct)
                acc[qb][ct] += *(const f32x4*)&sb[((qb * 4 + ct) * 64 + lane) * 4];
        lh[0] += lbuf[qsub * 32 + l15];
        lh[1] += lbuf[qsub * 32 + 16 + l15];
        int b = bh / 6, h = bh % 6;
#pragma unroll
        for (int qb = 0; qb < 2; ++qb) {
            float li[4];
            for (int r = 0; r < 4; ++r) li[r] = 1.0f / __shfl(lh[qb], quad * 4 + r);
            for (int ct = 0; ct < 4; ++ct)
                for (int r = 0; r < 4; ++r) {
                    int row = q0 + qsub * 32 + qb * 16 + quad * 4 + r;
                    int dh = ct * 16 + l15;
                    O[(b * 2048 + row) * 384 + h * 64 + dh] = f2bf(acc[qb][ct][r] * li[r]);
                }
        }
    }
}

// ---------------------------------------------------------------------------
// Kernel 3: out projection.  R17: LDS-free direct-load (same rationale as
// qkv: A = 12.6MB bf16 L3-resident, W = 0.29MB L2-resident), swapped MFMA
// operands (R16-proven) -> col on quad*4+r => f32x4 16B stores (4x fewer
// store instrs, 4x granule).  Tile 128x64, grid (128,6) = 768 blocks, 3/CU.
// ---------------------------------------------------------------------------
__global__ __launch_bounds__(256)
void outproj_kernel(const u16* __restrict__ A, const u16* __restrict__ Wob,
                    const float* __restrict__ B, float* __restrict__ out)
{
    const int tid = threadIdx.x;
    const int m0 = blockIdx.x * 128;
    const int n0 = blockIdx.y * 64;
    const int wv = tid >> 6, lane = tid & 63;
    const int l15 = lane & 15, quad = lane >> 4;
    const int mw = (wv & 1) * 64, nw = (wv >> 1) * 32;

    const u16* ab = &A[(m0 + mw + l15) * 384 + quad * 8];
    const u16* wb = &Wob[(n0 + nw + l15) * 384 + quad * 8];

    f32x4 acc[4][2] = {};                         // [mi][nj]
#pragma unroll
    for (int ks = 0; ks < 12; ++ks) {             // k-steps of 32
        const int ko = ks * 32;
        bf16x8 a[4], bf[2];
#pragma unroll
        for (int mi = 0; mi < 4; ++mi)
            a[mi] = *(const bf16x8*)(ab + mi * 16 * 384 + ko);
#pragma unroll
        for (int nj = 0; nj < 2; ++nj)
            bf[nj] = *(const bf16x8*)(wb + nj * 16 * 384 + ko);
#pragma unroll
        for (int mi = 0; mi < 4; ++mi)
#pragma unroll
            for (int nj = 0; nj < 2; ++nj)
                acc[mi][nj] = MFMA(bf[nj], a[mi], acc[mi][nj]);  // SWAPPED
    }
#pragma unroll
    for (int nj = 0; nj < 2; ++nj) {
        const int colb = n0 + nw + nj * 16 + quad * 4;   // + r
        const f32x4 bv = *(const f32x4*)&B[colb];
#pragma unroll
        for (int mi = 0; mi < 4; ++mi) {
            const int gm = m0 + mw + mi * 16 + l15;
            f32x4 o = acc[mi][nj];
#pragma unroll
            for (int r = 0; r < 4; ++r) o[r] += bv[r];
            *(f32x4*)&out[gm * 384 + colb] = o;   // 16B aligned
        }
    }
}

// ---------------------------------------------------------------------------
extern "C" void kernel_launch(void* const* d_in, const int* in_sizes, int n_in,
                              void* d_out, int out_size, void* d_ws, size_t ws_size,
                              hipStream_t stream) {
    const float* x     = (const float*)d_in[0];
    const float* w_qkv = (const float*)d_in[1];
    const float* b_qkv = (const float*)d_in[2];
    const float* w_out = (const float*)d_in[3];
    const float* b_out = (const float*)d_in[4];
    float* out = (float*)d_out;

    char* ws = (char*)d_ws;
    u16* Qw   = (u16*)(ws);                   // 12.58 MB
    u16* Kw   = (u16*)(ws + 12582912);        // 12.58 MB
    u16* VTw  = (u16*)(ws + 25165824);        // 12.58 MB  V^T [bh][64][2048], sigma-permuted keys
    u16* XbAw = (u16*)(ws + 37748736);        // 12.58 MB  Xb, later reused as Aw
    u16* Wqb  = (u16*)(ws + 50331648);        // 0.88 MB
    u16* Wob  = (u16*)(ws + 51216384);        // 0.29 MB

    cvt_kernel<<<6720, 256, 0, stream>>>(x, w_qkv, w_out, XbAw, Wqb, Wob);
    qkv_kernel<<<dim3(128, 9), 256, 0, stream>>>(XbAw, Wqb, b_qkv, Qw, Kw, VTw);
    attn_kernel<<<dim3(16, 48), 512, 0, stream>>>(Qw, Kw, VTw, XbAw);
    outproj_kernel<<<dim3(128, 6), 256, 0, stream>>>(XbAw, Wob, b_out, out);
}

// Round 11
// 194.092 us; speedup vs baseline: 1.2240x; 1.2240x over previous
//
#include <hip/hip_runtime.h>

typedef unsigned short u16;
typedef unsigned int u32;
typedef float f32x4 __attribute__((ext_vector_type(4)));
typedef __bf16 bf16x8 __attribute__((ext_vector_type(8)));
typedef unsigned short u16x8 __attribute__((ext_vector_type(8)));
typedef unsigned short u16x4 __attribute__((ext_vector_type(4)));
typedef unsigned int u32x4 __attribute__((ext_vector_type(4)));

// hardware RNE f32->bf16 (R6-proven)
__device__ inline u16 f2bf(float f) {
    return __builtin_bit_cast(u16, (__bf16)f);
}

// async global->LDS DMA, 16B/lane; LDS dst is wave-uniform base + lane*16.
__device__ inline void gll16(const u16* g, u16* l) {
    u16* gnc = const_cast<u16*>(g);
    __builtin_amdgcn_global_load_lds((__attribute__((address_space(1))) u32*)gnc,
                                     (__attribute__((address_space(3))) u32*)l,
                                     16, 0, 0);
}

#define MFMA(a, b, c) __builtin_amdgcn_mfma_f32_16x16x32_bf16((a), (b), (c), 0, 0, 0)

// Fixed-shift softmax (R5-R8 proven): p = exp2(q'.k - C_SHIFT),
// q' = q * 0.125*log2(e).  Shift-invariant => exact.
#define C_SHIFT 17.3123405f
#define Q_SCALE 0.1803368801f   // 0.125 * log2(e)

// ---------------------------------------------------------------------------
// Kernel 0: one-shot fp32->bf16 conversion of X, w_qkv, w_out. (R7-proven)
// ---------------------------------------------------------------------------
__global__ __launch_bounds__(256)
void cvt_kernel(const float* __restrict__ X, const float* __restrict__ Wq,
                const float* __restrict__ Wo, u16* __restrict__ Xb,
                u16* __restrict__ Wqb, u16* __restrict__ Wob)
{
    int i = blockIdx.x * 256 + threadIdx.x;      // vec4 index
    const float* src; u16* dst; int off;
    if (i < 1572864)       { src = X;  dst = Xb;  off = i; }
    else if (i < 1683456)  { src = Wq; dst = Wqb; off = i - 1572864; }
    else                   { src = Wo; dst = Wob; off = i - 1683456; }
    f32x4 v = *(const f32x4*)&src[off * 4];
    u16x4 p;
    for (int k = 0; k < 4; ++k) p[k] = f2bf(v[k]);
    *(u16x4*)&dst[off * 4] = p;
}

// ---------------------------------------------------------------------------
// Kernel 1: QKV projection, 128x128 tile.  R18 = R16 kernel body verbatim
// (single-buffer gll16 staging, swapped MFMA operands, vectorized epilogue)
// + L2-locality dispatch swizzle: 1152 blocks = 8 XCD x 144; the 9 blocks
// sharing an X-slab (same m0) become CONSECUTIVE on one XCD, so the slab's
// 9 uses are L2-resident (R7: FETCH 56.8MB vs 13.5MB minimum = ~4x X
// re-fetch with the old 128-slot-apart schedule).
// ---------------------------------------------------------------------------
__global__ __launch_bounds__(256)
void qkv_kernel(const u16* __restrict__ Xb, const u16* __restrict__ Wqb,
                const float* __restrict__ B, u16* __restrict__ Qo,
                u16* __restrict__ Ko, u16* __restrict__ VTo)
{
    __shared__ __align__(128) u16 As[128][64];
    __shared__ __align__(128) u16 Ws[128][64];
    const int tid = threadIdx.x;
    // L2 swizzle: lin = dispatch index; lin2 consecutive within one XCD,
    // 9 consecutive lin2 share m0 (X-slab) -> immediate L2 reuse.
    const int lin = blockIdx.y * 128 + blockIdx.x;
    const int lin2 = (lin & 7) * 144 + (lin >> 3);
    const int m0 = (lin2 / 9) * 128;
    const int n0 = (lin2 % 9) * 128;              // 9 tiles over 1152
    const int wv = tid >> 6, lane = tid & 63;
    const int l15 = lane & 15, quad = lane >> 4;
    const int mw = (wv & 1) * 64, nw = (wv >> 1) * 64;

    // staging: lane writes LDS row R0+(lane>>3), group lane&7; fetch the
    // source group (lane&7)^(lane>>3) so reads can un-swizzle.  (R10-proven)
    const int lr = lane >> 3;
    const int gsrc = (lane & 7) ^ lr;
    const int swz = (quad ^ (l15 & 7)) * 8;       // swizzled col for group=quad

    f32x4 acc[4][4] = {};                         // [mi][nj]; D[n-dim][m-dim]
    for (int kt = 0; kt < 384; kt += 64) {
        __syncthreads();                          // prev-tile reads done
#pragma unroll
        for (int i = 0; i < 4; ++i) {
            int r = (wv * 4 + i) * 8 + lr;        // 0..127
            gll16(&Xb[(m0 + r) * 384 + kt + gsrc * 8], &As[(wv * 4 + i) * 8][0]);
            gll16(&Wqb[(n0 + r) * 384 + kt + gsrc * 8], &Ws[(wv * 4 + i) * 8][0]);
        }
        __syncthreads();                          // vmcnt(0) drain -> tile visible
#pragma unroll
        for (int kc = 0; kc < 2; ++kc) {
            bf16x8 a[4], bf[4];
#pragma unroll
            for (int mi = 0; mi < 4; ++mi)
                a[mi] = *(const bf16x8*)&As[mw + mi * 16 + l15][swz ^ (kc << 5)];
#pragma unroll
            for (int nj = 0; nj < 4; ++nj)
                bf[nj] = *(const bf16x8*)&Ws[nw + nj * 16 + l15][swz ^ (kc << 5)];
#pragma unroll
            for (int mi = 0; mi < 4; ++mi)
#pragma unroll
                for (int nj = 0; nj < 4; ++nj)
                    acc[mi][nj] = MFMA(bf[nj], a[mi], acc[mi][nj]);  // SWAPPED
        }
    }
    // epilogue (R16-proven): D[col = n0+nw+nj*16+quad*4+r][row gm = ...+l15]
#pragma unroll
    for (int nj = 0; nj < 4; ++nj) {
        const int colb = n0 + nw + nj * 16 + quad * 4;   // + r, r=0..3
        const int t = colb / 384;                 // uniform per (block,wv,nj)
        const int hd = (colb % 384) / 64;         // head, uniform (16-block)
        const int dh0 = colb & 63;                // per-quad, +r consecutive
        const f32x4 bv = *(const f32x4*)&B[colb]; // aligned: colb % 4 == 0
#pragma unroll
        for (int mi = 0; mi < 4; ++mi) {
            const int gm = m0 + mw + mi * 16 + l15;
            const int bb = gm >> 11, n = gm & 2047;
            const int bh = bb * 6 + hd;
            if (t == 0) {
                u16x4 p;
#pragma unroll
                for (int r = 0; r < 4; ++r)
                    p[r] = f2bf((acc[mi][nj][r] + bv[r]) * Q_SCALE);
                *(u16x4*)&Qo[(bh * 2048 + n) * 64 + dh0] = p;
            } else if (t == 1) {
                u16x4 p;
#pragma unroll
                for (int r = 0; r < 4; ++r)
                    p[r] = f2bf(acc[mi][nj][r] + bv[r]);
                *(u16x4*)&Ko[(bh * 2048 + n) * 64 + dh0] = p;
            } else {
                // sigma permutation of n within each 32-key half (R14):
                // key kk = c*16+q4*4+rr -> pos q4*8+c*4+rr
                const int nn = (n & ~31) | (((n >> 2) & 3) << 3)
                             | (((n >> 4) & 1) << 2) | (n & 3);
#pragma unroll
                for (int r = 0; r < 4; ++r)
                    VTo[(bh * 64 + dh0 + r) * 2048 + nn] =
                        f2bf(acc[mi][nj][r] + bv[r]);
            }
        }
    }
}

// ---------------------------------------------------------------------------
// Kernel 2: flash attention.  R14 (FROZEN control at ~76us, bank conflicts
// == 0).  In-register P via key-permuted VT (sigma) and pi-ordered PV
// operands; key-split waves; single-barrier dbuf gll16 staging.
// ---------------------------------------------------------------------------
__global__ __launch_bounds__(512)
void attn_kernel(const u16* __restrict__ Q, const u16* __restrict__ K,
                 const u16* __restrict__ VT, u16* __restrict__ O)
{
    __shared__ __align__(128) u16 Ks[2][64][64];
    __shared__ __align__(128) u16 VTs[2][64][64];
    __shared__ __align__(16) float lbuf[128];

    const int tid = threadIdx.x;
    // XCD swizzle: lin = by*16+bx; xcd = lin%8 gets contiguous lin2 chunk.
    const int lin = blockIdx.y * 16 + blockIdx.x;
    const int lin2 = (lin & 7) * 96 + (lin >> 3);
    const int bh = lin2 >> 4;
    const int q0 = (lin2 & 15) * 128;
    const int wv = tid >> 6, lane = tid & 63;
    const int l15 = lane & 15, quad = lane >> 4;
    const int qsub = wv & 3, kh = wv >> 2;

    // Q fragments for this wave's 32 q-rows (B-operand: n=l15, k=quad*8+j)
    bf16x8 qf[2][2];
#pragma unroll
    for (int qb = 0; qb < 2; ++qb) {
        const u16* qptr = &Q[(bh * 2048 + q0 + qsub * 32 + qb * 16 + l15) * 64 + quad * 8];
        qf[qb][0] = *(const bf16x8*)qptr;
        qf[qb][1] = *(const bf16x8*)(qptr + 32);
    }

    // gll staging: wave wv covers rows wv*8 .. wv*8+7 (1KB) of each buffer.
    const int lr = lane >> 3;
    const int gsrc = (lane & 7) ^ lr;
    const u16* ksrc = &K[(bh * 2048 + wv * 8 + lr) * 64 + gsrc * 8];   // +4096/tile
    const u16* vsrc = &VT[(bh * 64 + wv * 8 + lr) * 2048 + gsrc * 8];  // +64/tile
    const int swz = (quad ^ (l15 & 7)) * 8;                  // read-side swizzle

    const f32x4 cinit = {-C_SHIFT, -C_SHIFT, -C_SHIFT, -C_SHIFT};
    float l_part[2] = {};
    f32x4 acc[2][4] = {};                     // [qb][ct=dh-block], key-half partial

    // prologue: stage tile 0 into buffer 0
    gll16(ksrc, &Ks[0][wv * 8][0]);
    gll16(vsrc, &VTs[0][wv * 8][0]);

    for (int j = 0; j < 32; ++j) {
        const int cur = j & 1;
        __syncthreads();
        if (j < 31) {
            gll16(ksrc + (j + 1) * 4096, &Ks[cur ^ 1][wv * 8][0]);
            gll16(vsrc + (j + 1) * 64, &VTs[cur ^ 1][wv * 8][0]);
        }

        // S^T over this wave's key-half: key = kh*32 + c*16 + quad*4 + r,
        // q = l15.  exp2 results packed straight into PV A-frag u32s.
        u32 w[2][2][2];                       // [qb][c][h]: keys (.. +2h, +2h+1)
#pragma unroll
        for (int c = 0; c < 2; ++c) {
            const u16* krow = &Ks[cur][kh * 32 + c * 16 + l15][0];
            bf16x8 a0 = *(const bf16x8*)(krow + swz);
            bf16x8 a1 = *(const bf16x8*)(krow + (swz ^ 32));
#pragma unroll
            for (int qb = 0; qb < 2; ++qb) {
                f32x4 s = MFMA(a0, qf[qb][0], cinit);
                s = MFMA(a1, qf[qb][1], s);
                float p0 = __builtin_amdgcn_exp2f(s[0]);
                float p1 = __builtin_amdgcn_exp2f(s[1]);
                float p2 = __builtin_amdgcn_exp2f(s[2]);
                float p3 = __builtin_amdgcn_exp2f(s[3]);
                l_part[qb] += p0;             // same add order as R12 (exact)
                l_part[qb] += p1;
                l_part[qb] += p2;
                l_part[qb] += p3;
                w[qb][c][0] = (u32)f2bf(p0) | ((u32)f2bf(p1) << 16);
                w[qb][c][1] = (u32)f2bf(p2) | ((u32)f2bf(p3) << 16);
            }
        }

        // PV A-frags: pure register renaming under pi (no shuffles, no LDS).
        bf16x8 pf[2];
#pragma unroll
        for (int qb = 0; qb < 2; ++qb) {
            u32x4 t = {w[qb][0][0], w[qb][0][1], w[qb][1][0], w[qb][1][1]};
            pf[qb] = __builtin_bit_cast(bf16x8, t);
        }

        // PV: B-frag = sigma-permuted VT under the same pi -> single
        // proven-swizzled b128 per dh-block, reused over 2 q-blocks.
#pragma unroll
        for (int ct = 0; ct < 4; ++ct) {
            bf16x8 bv = *(const bf16x8*)(&VTs[cur][ct * 16 + l15][0] + (swz ^ (kh << 5)));
#pragma unroll
            for (int qb = 0; qb < 2; ++qb)
                acc[qb][ct] = MFMA(pf[qb], bv, acc[qb][ct]);
        }
    }

    // ---- epilogue: cross-wave (key-half) reduction, then normalize+store.
    float lh[2];
#pragma unroll
    for (int qb = 0; qb < 2; ++qb) {
        float t = l_part[qb];
        t += __shfl_xor(t, 16);
        t += __shfl_xor(t, 32);
        lh[qb] = t;
    }
    __syncthreads();      // all waves done with Ks/VTs tile data
    if (kh == 1) {
        float* sb = (qsub < 2) ? (float*)&Ks[qsub][0][0] : (float*)&VTs[qsub - 2][0][0];
#pragma unroll
        for (int qb = 0; qb < 2; ++qb)
#pragma unroll
            for (int ct = 0; ct < 4; ++ct)
                *(f32x4*)&sb[((qb * 4 + ct) * 64 + lane) * 4] = acc[qb][ct];
        if (quad == 0) {
            lbuf[qsub * 32 + l15] = lh[0];
            lbuf[qsub * 32 + 16 + l15] = lh[1];
        }
    }
    __syncthreads();
    if (kh == 0) {
        float* sb = (qsub < 2) ? (float*)&Ks[qsub][0][0] : (float*)&VTs[qsub - 2][0][0];
#pragma unroll
        for (int qb = 0; qb < 2; ++qb)
#pragma unroll
            for (int ct = 0; ct < 4; ++ct)
                acc[qb][ct] += *(const f32x4*)&sb[((qb * 4 + ct) * 64 + lane) * 4];
        lh[0] += lbuf[qsub * 32 + l15];
        lh[1] += lbuf[qsub * 32 + 16 + l15];
        int b = bh / 6, h = bh % 6;
#pragma unroll
        for (int qb = 0; qb < 2; ++qb) {
            float li[4];
            for (int r = 0; r < 4; ++r) li[r] = 1.0f / __shfl(lh[qb], quad * 4 + r);
            for (int ct = 0; ct < 4; ++ct)
                for (int r = 0; r < 4; ++r) {
                    int row = q0 + qsub * 32 + qb * 16 + quad * 4 + r;
                    int dh = ct * 16 + l15;
                    O[(b * 2048 + row) * 384 + h * 64 + dh] = f2bf(acc[qb][ct][r] * li[r]);
                }
        }
    }
}

// ---------------------------------------------------------------------------
// Kernel 3: out projection (R5/R7-proven body) + R18 L2-locality dispatch
// swizzle: 1536 blocks = 8 XCD x 192; the 6 blocks sharing an A-slab become
// consecutive on one XCD (A = 12.6MB re-read 6x -> L2-resident slabs).
// ---------------------------------------------------------------------------
__global__ __launch_bounds__(256)
void outproj_kernel(const u16* __restrict__ A, const u16* __restrict__ Wob,
                    const float* __restrict__ B, float* __restrict__ out)
{
    __shared__ __align__(16) u16 As[64][72];
    __shared__ __align__(16) u16 Ws[64][72];
    const int tid = threadIdx.x;
    const int lin = blockIdx.y * 256 + blockIdx.x;
    const int lin2 = (lin & 7) * 192 + (lin >> 3);
    const int m0 = (lin2 / 6) * 64;
    const int n0 = (lin2 % 6) * 64;
    const int wv = tid >> 6, lane = tid & 63;
    const int l15 = lane & 15, quad = lane >> 4;

    f32x4 acc[4] = {};
    for (int kt = 0; kt < 384; kt += 64) {
        __syncthreads();
        for (int c = tid; c < 512; c += 256) {
            int row = c >> 3, cc = (c & 7) * 8;
            *(u16x8*)&As[row][cc] = *(const u16x8*)&A[(m0 + row) * 384 + kt + cc];
            *(u16x8*)&Ws[row][cc] = *(const u16x8*)&Wob[(n0 + row) * 384 + kt + cc];
        }
        __syncthreads();
        for (int kc = 0; kc < 2; ++kc) {
            bf16x8 b = *(const bf16x8*)&Ws[wv * 16 + l15][kc * 32 + quad * 8];
            for (int mi = 0; mi < 4; ++mi) {
                bf16x8 a = *(const bf16x8*)&As[mi * 16 + l15][kc * 32 + quad * 8];
                acc[mi] = MFMA(a, b, acc[mi]);
            }
        }
    }
    const int col = n0 + wv * 16 + l15;
    const float bias = B[col];
    for (int mi = 0; mi < 4; ++mi)
        for (int r = 0; r < 4; ++r) {
            int gm = m0 + mi * 16 + quad * 4 + r;
            out[gm * 384 + col] = acc[mi][r] + bias;
        }
}

// ---------------------------------------------------------------------------
extern "C" void kernel_launch(void* const* d_in, const int* in_sizes, int n_in,
                              void* d_out, int out_size, void* d_ws, size_t ws_size,
                              hipStream_t stream) {
    const float* x     = (const float*)d_in[0];
    const float* w_qkv = (const float*)d_in[1];
    const float* b_qkv = (const float*)d_in[2];
    const float* w_out = (const float*)d_in[3];
    const float* b_out = (const float*)d_in[4];
    float* out = (float*)d_out;

    char* ws = (char*)d_ws;
    u16* Qw   = (u16*)(ws);                   // 12.58 MB
    u16* Kw   = (u16*)(ws + 12582912);        // 12.58 MB
    u16* VTw  = (u16*)(ws + 25165824);        // 12.58 MB  V^T [bh][64][2048], sigma-permuted keys
    u16* XbAw = (u16*)(ws + 37748736);        // 12.58 MB  Xb, later reused as Aw
    u16* Wqb  = (u16*)(ws + 50331648);        // 0.88 MB
    u16* Wob  = (u16*)(ws + 51216384);        // 0.29 MB

    cvt_kernel<<<6720, 256, 0, stream>>>(x, w_qkv, w_out, XbAw, Wqb, Wob);
    qkv_kernel<<<dim3(128, 9), 256, 0, stream>>>(XbAw, Wqb, b_qkv, Qw, Kw, VTw);
    attn_kernel<<<dim3(16, 48), 512, 0, stream>>>(Qw, Kw, VTw, XbAw);
    outproj_kernel<<<dim3(256, 6), 256, 0, stream>>>(XbAw, Wob, b_out, out);
}